// Round 1
// baseline (61.826 us; speedup 1.0000x reference)
//
#include <hip/hip_runtime.h>
#include <hip/hip_bf16.h>

#define N_ROWS 8192
#define DIM 128
#define MARGIN_F 0.3f

typedef __attribute__((ext_vector_type(8))) short short8;
typedef __attribute__((ext_vector_type(4))) float f32x4;

typedef const void __attribute__((address_space(1)))* gas1_t;
typedef void __attribute__((address_space(3)))* las3_t;

__device__ __forceinline__ void load_lds16(const void* g, void* l) {
  __builtin_amdgcn_global_load_lds((gas1_t)g, (las3_t)l, 16, 0, 0);
}

// ---------------- Kernel A: fp32 -> bf16, row norms, init ap/an ------------
__global__ __launch_bounds__(256) void prep_kernel(
    const float* __restrict__ x, unsigned short* __restrict__ xb,
    float* __restrict__ sq, int* __restrict__ apb, int* __restrict__ anb) {
  const int w = threadIdx.x >> 6, l = threadIdx.x & 63;
  const int row = blockIdx.x * 4 + w;
  const float2* xp = reinterpret_cast<const float2*>(x + (size_t)row * DIM);
  float2 v = xp[l];
  __hip_bfloat16 b0 = __float2bfloat16(v.x);
  __hip_bfloat16 b1 = __float2bfloat16(v.y);
  ushort2 st;
  st.x = *reinterpret_cast<unsigned short*>(&b0);
  st.y = *reinterpret_cast<unsigned short*>(&b1);
  reinterpret_cast<ushort2*>(xb)[(size_t)row * 64 + l] = st;
  float s = v.x * v.x + v.y * v.y;
  #pragma unroll
  for (int off = 32; off >= 1; off >>= 1) s += __shfl_xor(s, off);
  if (l == 0) {
    sq[row] = s;
    apb[row] = 0x00000000;   // 0.0f  (max identity; every row has its diagonal positive)
    anb[row] = 0x7f800000;   // +inf  (min identity)
  }
}

// ---------------- Kernel B: fused Gram (bf16 MFMA) + batch-hard mining -----
// grid (64 row-blocks, 8 col-chunks); block 256 = 4 waves in 2x2;
// wave computes 64x64 of S per col-tile; A frags (K=128) live in registers.
__global__ __launch_bounds__(256, 2) void gram_mine_kernel(
    const unsigned short* __restrict__ xb, const float* __restrict__ sq,
    const int* __restrict__ tgt, int* __restrict__ apb, int* __restrict__ anb) {
  __shared__ unsigned short Bs[2][128 * 128];  // 2 x 32KB, XOR-swizzled rows

  const int t = threadIdx.x;
  const int w = t >> 6, l = t & 63;
  const int wr = w >> 1, wc = w & 1;
  const int l15 = l & 15, l4 = l >> 4;
  const int rb = blockIdx.x * 128 + wr * 64;       // wave's global row base
  const int chunkbase = blockIdx.y * 1024;         // 1024 cols per chunk

  // A fragments: rows rb + rf*16 + l15, k = kk*32 + l4*8 (contiguous 8 bf16)
  short8 a[4][4];
  #pragma unroll
  for (int rf = 0; rf < 4; ++rf) {
    const short8* p = reinterpret_cast<const short8*>(xb + (size_t)(rb + rf * 16 + l15) * DIM);
    #pragma unroll
    for (int kk = 0; kk < 4; ++kk) a[rf][kk] = p[kk * 4 + l4];
  }
  // per-lane row metadata (C/D layout rows: rb + rf*16 + l4*4 + rg)
  float sq_r[16]; int t_r[16];
  #pragma unroll
  for (int rf = 0; rf < 4; ++rf)
    #pragma unroll
    for (int rg = 0; rg < 4; ++rg) {
      int row = rb + rf * 16 + l4 * 4 + rg;
      sq_r[rf * 4 + rg] = sq[row];
      t_r[rf * 4 + rg] = tgt[row];
    }

  float ap2[16], an2[16];
  #pragma unroll
  for (int i = 0; i < 16; ++i) { ap2[i] = -__builtin_inff(); an2[i] = __builtin_inff(); }

  // stage col-tile ct into buffer buf (128 cols x 128 k bf16 = 32KB, swizzled)
  auto stage = [&](int buf, int ct) {
    const int colbase = chunkbase + ct * 128;
    #pragma unroll
    for (int r = 0; r < 8; ++r) {
      int c = r * 256 + t;                 // 16B-chunk index 0..2047
      int col_local = c >> 4;
      int off = ((c & 15) * 16) ^ ((col_local & 7) << 4);   // pre-swizzled source
      const char* src = reinterpret_cast<const char*>(xb) +
                        (size_t)(colbase + col_local) * 256 + off;
      load_lds16(src, (char*)(&Bs[buf][0]) + c * 16);       // linear LDS dest
    }
  };

  stage(0, 0);
  int cur = 0;
  for (int ct = 0; ct < 8; ++ct) {
    __syncthreads();                       // drains vmcnt: Bs[cur] ready
    if (ct < 7) stage(cur ^ 1, ct + 1);    // prefetch overlaps compute

    f32x4 acc[4][4];
    #pragma unroll
    for (int rf = 0; rf < 4; ++rf)
      #pragma unroll
      for (int cf = 0; cf < 4; ++cf) acc[rf][cf] = (f32x4){0.f, 0.f, 0.f, 0.f};

    #pragma unroll
    for (int kk = 0; kk < 4; ++kk) {
      short8 b[4];
      #pragma unroll
      for (int cf = 0; cf < 4; ++cf) {
        int col_local = wc * 64 + cf * 16 + l15;
        int kb = (kk * 64 + l4 * 16) ^ ((col_local & 7) << 4);
        b[cf] = *reinterpret_cast<const short8*>(
            reinterpret_cast<const char*>(&Bs[cur][0]) + col_local * 256 + kb);
      }
      #pragma unroll
      for (int rf = 0; rf < 4; ++rf)
        #pragma unroll
        for (int cf = 0; cf < 4; ++cf)
          acc[rf][cf] = __builtin_amdgcn_mfma_f32_16x16x32_bf16(
              a[rf][kk], b[cf], acc[rf][cf], 0, 0, 0);
    }

    // mining epilogue on d^2 (sqrt/clamp deferred; both monotone)
    const int colbase = chunkbase + ct * 128;
    #pragma unroll
    for (int cf = 0; cf < 4; ++cf) {
      int colg = colbase + wc * 64 + cf * 16 + l15;
      float sqc = sq[colg];
      int tc = tgt[colg];
      #pragma unroll
      for (int rf = 0; rf < 4; ++rf)
        #pragma unroll
        for (int rg = 0; rg < 4; ++rg) {
          int idx = rf * 4 + rg;
          float d2 = fmaf(-2.f, acc[rf][cf][rg], sq_r[idx] + sqc);
          bool pos = (t_r[idx] == tc);
          ap2[idx] = pos ? fmaxf(ap2[idx], d2) : ap2[idx];
          an2[idx] = pos ? an2[idx] : fminf(an2[idx], d2);
        }
    }
    cur ^= 1;
  }

  // reduce across the 16 lanes (same l4 group = same rows, different cols)
  #pragma unroll
  for (int i = 0; i < 16; ++i) {
    #pragma unroll
    for (int off = 1; off < 16; off <<= 1) {
      ap2[i] = fmaxf(ap2[i], __shfl_xor(ap2[i], off));
      an2[i] = fminf(an2[i], __shfl_xor(an2[i], off));
    }
  }
  if (l15 == 0) {
    #pragma unroll
    for (int rf = 0; rf < 4; ++rf)
      #pragma unroll
      for (int rg = 0; rg < 4; ++rg) {
        int row = rb + rf * 16 + l4 * 4 + rg;
        // clamp to >=1e-12 (commutes with max/min): all values non-negative ->
        // IEEE bit pattern is int-monotone -> int atomics give exact fp max/min
        float a2 = fmaxf(ap2[rf * 4 + rg], 1e-12f);
        float n2 = fmaxf(an2[rf * 4 + rg], 1e-12f);
        atomicMax(apb + row, __float_as_int(a2));
        atomicMin(anb + row, __float_as_int(n2));
      }
  }
}

// ---------------- Kernel C: loss = mean(relu(sqrt(ap2)-sqrt(an2)+margin)) --
__global__ __launch_bounds__(1024) void loss_kernel(
    const int* __restrict__ apb, const int* __restrict__ anb, float* __restrict__ out) {
  __shared__ float red[16];
  float s = 0.f;
  for (int i = threadIdx.x; i < N_ROWS; i += 1024) {
    float ap = sqrtf(__int_as_float(apb[i]));
    float an = sqrtf(__int_as_float(anb[i]));   // +inf if no negatives -> relu(-inf)=0
    float li = ap - an + MARGIN_F;
    s += li > 0.f ? li : 0.f;
  }
  #pragma unroll
  for (int off = 32; off >= 1; off >>= 1) s += __shfl_xor(s, off);
  const int w = threadIdx.x >> 6, l = threadIdx.x & 63;
  if (l == 0) red[w] = s;
  __syncthreads();
  if (threadIdx.x < 16) {
    float v = red[threadIdx.x];
    #pragma unroll
    for (int off = 8; off >= 1; off >>= 1) v += __shfl_xor(v, off);
    if (threadIdx.x == 0) out[0] = v / (float)N_ROWS;
  }
}

extern "C" void kernel_launch(void* const* d_in, const int* in_sizes, int n_in,
                              void* d_out, int out_size, void* d_ws, size_t ws_size,
                              hipStream_t stream) {
  const float* x = (const float*)d_in[0];
  const int* tgt = (const int*)d_in[1];
  float* out = (float*)d_out;

  char* ws = (char*)d_ws;
  unsigned short* xb = (unsigned short*)ws;                 // 2 MB bf16 copy
  float* sq = (float*)(ws + 2097152);                       // 32 KB row norms
  int* apb = (int*)(ws + 2097152 + 32768);                  // 32 KB ap^2 bits
  int* anb = (int*)(ws + 2097152 + 65536);                  // 32 KB an^2 bits

  prep_kernel<<<2048, 256, 0, stream>>>(x, xb, sq, apb, anb);
  gram_mine_kernel<<<dim3(64, 8), 256, 0, stream>>>(xb, sq, tgt, apb, anb);
  loss_kernel<<<1, 1024, 0, stream>>>(apb, anb, out);
}

// Round 2
// 52.253 us; speedup vs baseline: 1.1832x; 1.1832x over previous
//
#include <hip/hip_runtime.h>
#include <hip/hip_bf16.h>

#define N_ROWS 8192
#define DIM 128
#define MARGIN_F 0.3f

typedef __attribute__((ext_vector_type(8))) short short8;
typedef __attribute__((ext_vector_type(4))) float f32x4;
typedef __attribute__((ext_vector_type(4))) int int4v;

typedef const void __attribute__((address_space(1)))* gas1_t;
typedef void __attribute__((address_space(3)))* las3_t;

__device__ __forceinline__ void load_lds16(const void* g, void* l) {
  __builtin_amdgcn_global_load_lds((gas1_t)g, (las3_t)l, 16, 0, 0);
}

// ---------------- Kernel A: fp32 -> bf16, row norms+targets, init ap/an ----
__global__ __launch_bounds__(256) void prep_kernel(
    const float* __restrict__ x, const int* __restrict__ tgt,
    unsigned short* __restrict__ xb, float2* __restrict__ meta,
    int* __restrict__ apb, int* __restrict__ anb) {
  const int w = threadIdx.x >> 6, l = threadIdx.x & 63;
  const int row = blockIdx.x * 4 + w;
  const float2* xp = reinterpret_cast<const float2*>(x + (size_t)row * DIM);
  float2 v = xp[l];
  __hip_bfloat16 b0 = __float2bfloat16(v.x);
  __hip_bfloat16 b1 = __float2bfloat16(v.y);
  ushort2 st;
  st.x = *reinterpret_cast<unsigned short*>(&b0);
  st.y = *reinterpret_cast<unsigned short*>(&b1);
  reinterpret_cast<ushort2*>(xb)[(size_t)row * 64 + l] = st;
  float s = v.x * v.x + v.y * v.y;
  #pragma unroll
  for (int off = 32; off >= 1; off >>= 1) s += __shfl_xor(s, off);
  if (l == 0) {
    float2 m;
    m.x = s;
    m.y = __int_as_float(tgt[row]);   // raw bit carry; only ever bit-compared
    meta[row] = m;
    apb[row] = 0x00000000;            // 0.0f (max identity; diagonal always positive)
    anb[row] = 0x7f800000;            // +inf (min identity)
  }
}

// ---------------- Kernel B: fused Gram (bf16 MFMA) + batch-hard mining -----
// grid (64 row-blocks, 16 col-chunks) = 1024 blocks -> 4 blocks/CU.
// block 256 = 4 waves stacked in rows; wave = 32 rows x 64 cols per tile;
// A frags (K=128) in registers; B (64 cols x 128 k) staged via
// global_load_lds into XOR-swizzled LDS, double-buffered (2 x 16 KB).
__global__ __launch_bounds__(256, 4) void gram_mine_kernel(
    const unsigned short* __restrict__ xb, const float2* __restrict__ meta,
    int* __restrict__ apb, int* __restrict__ anb) {
  __shared__ unsigned short Bs[2][64 * 128];  // 2 x 16 KB

  const int t = threadIdx.x;
  const int w = t >> 6, l = t & 63;
  const int l15 = l & 15, l4 = l >> 4;
  const int rb = blockIdx.x * 128 + w * 32;      // wave's global row base
  const int chunkbase = blockIdx.y * 512;        // 512 cols per chunk (8 tiles)

  // A fragments: rows rb + rf*16 + l15, k = kk*32 + l4*8 (contiguous 8 bf16)
  short8 a[2][4];
  #pragma unroll
  for (int rf = 0; rf < 2; ++rf) {
    const short8* p = reinterpret_cast<const short8*>(xb + (size_t)(rb + rf * 16 + l15) * DIM);
    #pragma unroll
    for (int kk = 0; kk < 4; ++kk) a[rf][kk] = p[kk * 4 + l4];
  }
  // per-lane row classes (C/D layout rows: rb + rf*16 + l4*4 + rg)
  int t_r[8];
  #pragma unroll
  for (int rf = 0; rf < 2; ++rf)
    #pragma unroll
    for (int rg = 0; rg < 4; ++rg)
      t_r[rf * 4 + rg] = __float_as_int(meta[rb + rf * 16 + l4 * 4 + rg].y);

  // mining state on v = sqc - 2*s  (row term +sq_r deferred to the end)
  float ap2[8], an2[8];
  #pragma unroll
  for (int i = 0; i < 8; ++i) { ap2[i] = -__builtin_inff(); an2[i] = __builtin_inff(); }

  // stage col-tile ct into buffer buf (64 cols x 128 k bf16 = 16 KB, swizzled)
  auto stage = [&](int buf, int ct) {
    const int colbase = chunkbase + ct * 64;
    #pragma unroll
    for (int r = 0; r < 4; ++r) {
      int c = r * 256 + t;                 // 16B-chunk index 0..1023
      int col_local = c >> 4;
      int off = ((c & 15) * 16) ^ ((col_local & 7) << 4);   // pre-swizzled source
      const char* src = reinterpret_cast<const char*>(xb) +
                        (size_t)(colbase + col_local) * 256 + off;
      load_lds16(src, (char*)(&Bs[buf][0]) + c * 16);       // linear LDS dest
    }
  };

  stage(0, 0);
  int cur = 0;
  for (int ct = 0; ct < 8; ++ct) {
    __syncthreads();                       // drains vmcnt: Bs[cur] ready
    if (ct < 7) stage(cur ^ 1, ct + 1);    // prefetch overlaps compute

    // column metadata: issue early so loads fly during the MFMAs
    const int colbase = chunkbase + ct * 64;
    float sqc[4]; int tc[4];
    #pragma unroll
    for (int cf = 0; cf < 4; ++cf) {
      float2 m = meta[colbase + cf * 16 + l15];
      sqc[cf] = m.x; tc[cf] = __float_as_int(m.y);
    }

    f32x4 acc[2][4];
    #pragma unroll
    for (int rf = 0; rf < 2; ++rf)
      #pragma unroll
      for (int cf = 0; cf < 4; ++cf) acc[rf][cf] = (f32x4){0.f, 0.f, 0.f, 0.f};

    #pragma unroll
    for (int kk = 0; kk < 4; ++kk) {
      #pragma unroll
      for (int cf = 0; cf < 4; ++cf) {
        int col_local = cf * 16 + l15;
        int kb = (kk * 64 + l4 * 16) ^ ((col_local & 7) << 4);
        short8 b = *reinterpret_cast<const short8*>(
            reinterpret_cast<const char*>(&Bs[cur][0]) + col_local * 256 + kb);
        #pragma unroll
        for (int rf = 0; rf < 2; ++rf)
          acc[rf][cf] = __builtin_amdgcn_mfma_f32_16x16x32_bf16(
              a[rf][kk], b, acc[rf][cf], 0, 0, 0);
      }
    }

    // mining epilogue on v = sqc - 2s (monotone in d^2 per row)
    #pragma unroll
    for (int cf = 0; cf < 4; ++cf) {
      #pragma unroll
      for (int rf = 0; rf < 2; ++rf)
        #pragma unroll
        for (int rg = 0; rg < 4; ++rg) {
          int idx = rf * 4 + rg;
          float v = fmaf(-2.f, acc[rf][cf][rg], sqc[cf]);
          bool pos = (t_r[idx] == tc[cf]);
          ap2[idx] = pos ? fmaxf(ap2[idx], v) : ap2[idx];
          an2[idx] = pos ? an2[idx] : fminf(an2[idx], v);
        }
    }
    cur ^= 1;
  }

  // reduce across the 16 lanes (same l4 group = same rows, different cols)
  #pragma unroll
  for (int i = 0; i < 8; ++i) {
    #pragma unroll
    for (int off = 1; off < 16; off <<= 1) {
      ap2[i] = fmaxf(ap2[i], __shfl_xor(ap2[i], off));
      an2[i] = fminf(an2[i], __shfl_xor(an2[i], off));
    }
  }
  if (l15 == 0) {
    #pragma unroll
    for (int rf = 0; rf < 2; ++rf)
      #pragma unroll
      for (int rg = 0; rg < 4; ++rg) {
        int row = rb + rf * 16 + l4 * 4 + rg;
        float sqr = meta[row].x;
        // d^2 = v + sq_r; clamp >=1e-12 commutes with max/min; non-negative
        // floats are int-monotone -> int atomics give exact fp max/min.
        float a2 = fmaxf(ap2[rf * 4 + rg] + sqr, 1e-12f);
        float n2 = fmaxf(an2[rf * 4 + rg] + sqr, 1e-12f);
        atomicMax(apb + row, __float_as_int(a2));
        atomicMin(anb + row, __float_as_int(n2));
      }
  }
}

// ---------------- Kernel C: loss = mean(relu(sqrt(ap2)-sqrt(an2)+margin)) --
__global__ __launch_bounds__(1024) void loss_kernel(
    const int4v* __restrict__ apb, const int4v* __restrict__ anb,
    float* __restrict__ out) {
  __shared__ float red[16];
  float s = 0.f;
  for (int i = threadIdx.x; i < N_ROWS / 4; i += 1024) {
    int4v a4 = apb[i], n4 = anb[i];
    #pragma unroll
    for (int j = 0; j < 4; ++j) {
      float ap = sqrtf(__int_as_float(a4[j]));
      float an = sqrtf(__int_as_float(n4[j]));   // +inf sentinel -> relu(-inf)=0
      float li = ap - an + MARGIN_F;
      s += li > 0.f ? li : 0.f;
    }
  }
  #pragma unroll
  for (int off = 32; off >= 1; off >>= 1) s += __shfl_xor(s, off);
  const int w = threadIdx.x >> 6, l = threadIdx.x & 63;
  if (l == 0) red[w] = s;
  __syncthreads();
  if (threadIdx.x < 16) {
    float v = red[threadIdx.x];
    #pragma unroll
    for (int off = 8; off >= 1; off >>= 1) v += __shfl_xor(v, off);
    if (threadIdx.x == 0) out[0] = v / (float)N_ROWS;
  }
}

extern "C" void kernel_launch(void* const* d_in, const int* in_sizes, int n_in,
                              void* d_out, int out_size, void* d_ws, size_t ws_size,
                              hipStream_t stream) {
  const float* x = (const float*)d_in[0];
  const int* tgt = (const int*)d_in[1];
  float* out = (float*)d_out;

  char* ws = (char*)d_ws;
  unsigned short* xb = (unsigned short*)ws;                 // 2 MB bf16 copy
  float2* meta = (float2*)(ws + 2097152);                   // 64 KB (sq, tgt)
  int* apb = (int*)(ws + 2097152 + 65536);                  // 32 KB ap^2 bits
  int* anb = (int*)(ws + 2097152 + 65536 + 32768);          // 32 KB an^2 bits

  prep_kernel<<<2048, 256, 0, stream>>>(x, tgt, xb, meta, apb, anb);
  gram_mine_kernel<<<dim3(64, 16), 256, 0, stream>>>(xb, meta, apb, anb);
  loss_kernel<<<1, 1024, 0, stream>>>((const int4v*)apb, (const int4v*)anb, out);
}

// Round 3
// 51.298 us; speedup vs baseline: 1.2052x; 1.0186x over previous
//
#include <hip/hip_runtime.h>
#include <hip/hip_bf16.h>

#define N_ROWS 8192
#define DIM 128
#define MARGIN_F 0.3f

typedef __attribute__((ext_vector_type(8))) short short8;
typedef __attribute__((ext_vector_type(4))) float f32x4;
typedef __attribute__((ext_vector_type(4))) int int4v;

// ---------------- Kernel A: fp32 -> bf16 (fragment-major), norms, init ----
// Fragment-major layout: 16B unit u = c16*256 + kk*64 + l4*16 + l15 holds
// bf16 elems [kk*32 + l4*8 .. +8) of row (c16*16 + l15). Then an MFMA
// A/B-fragment load for 16-row/col panel c16 is xf[c16*256 + kk*64 + lane]
// -- 64 lanes perfectly contiguous (1KB per global_load_dwordx4).
__global__ __launch_bounds__(256) void prep_kernel(
    const float* __restrict__ x, const int* __restrict__ tgt,
    unsigned short* __restrict__ xbB, float2* __restrict__ meta,
    int* __restrict__ apb, int* __restrict__ anb) {
  const int w = threadIdx.x >> 6, l = threadIdx.x & 63;
  const int row = blockIdx.x * 4 + w;
  float2 v = reinterpret_cast<const float2*>(x + (size_t)row * DIM)[l];
  __hip_bfloat16 b0 = __float2bfloat16(v.x);
  __hip_bfloat16 b1 = __float2bfloat16(v.y);
  ushort2 st;
  st.x = *reinterpret_cast<unsigned short*>(&b0);
  st.y = *reinterpret_cast<unsigned short*>(&b1);
  // lane l holds elems 2l,2l+1 = chunk (kk=l>>4, l4=(l>>2)&3), byte (l&3)*4
  const int c16 = row >> 4, l15r = row & 15;
  const int unit = c16 * 256 + (l >> 4) * 64 + ((l >> 2) & 3) * 16 + l15r;
  reinterpret_cast<ushort2*>(xbB)[unit * 4 + (l & 3)] = st;

  float s = v.x * v.x + v.y * v.y;
  #pragma unroll
  for (int off = 32; off >= 1; off >>= 1) s += __shfl_xor(s, off);
  if (l == 0) {
    float2 m;
    m.x = s;
    m.y = __int_as_float(tgt[row]);   // raw bit carry; only ever bit-compared
    meta[row] = m;
    apb[row] = 0x00000000;            // 0.0f (max identity; diagonal is positive)
    anb[row] = 0x7f800000;            // +inf (min identity)
  }
}

// ---------------- Kernel B: fused Gram (bf16 MFMA) + batch-hard mining -----
// NO LDS, NO barriers. grid (64 row-blocks, 16 col-chunks) = 1024 blocks.
// block 256 = 4 independent waves; wave = 32 rows x 64 cols per tile, 8 tiles.
// A frags (K=128) in registers; B frags streamed from L2 (2MB, resident)
// via coalesced fragment-major loads.
__global__ __launch_bounds__(256, 4) void gram_mine_kernel(
    const unsigned short* __restrict__ xbB, const float2* __restrict__ meta,
    int* __restrict__ apb, int* __restrict__ anb) {
  const int t = threadIdx.x;
  const int w = t >> 6, l = t & 63;
  const int l15 = l & 15, l4 = l >> 4;
  const int rb = blockIdx.x * 128 + w * 32;      // wave's global row base
  const int chunkbase = blockIdx.y * 512;        // 512 cols per chunk (8 tiles)

  const short8* xf = reinterpret_cast<const short8*>(xbB);  // 16B units

  // A fragments: panel c16 = rb/16 + rf
  short8 a[2][4];
  #pragma unroll
  for (int rf = 0; rf < 2; ++rf)
    #pragma unroll
    for (int kk = 0; kk < 4; ++kk)
      a[rf][kk] = xf[(rb >> 4 << 8) + rf * 256 + kk * 64 + l];

  // per-lane row classes (C/D layout rows: rb + rf*16 + l4*4 + rg)
  int t_r[8];
  #pragma unroll
  for (int rf = 0; rf < 2; ++rf)
    #pragma unroll
    for (int rg = 0; rg < 4; ++rg)
      t_r[rf * 4 + rg] = __float_as_int(meta[rb + rf * 16 + l4 * 4 + rg].y);

  // mining state on v = sqc - 2*s (row term +sq_r deferred to the end)
  float ap2[8], an2[8];
  #pragma unroll
  for (int i = 0; i < 8; ++i) { ap2[i] = -__builtin_inff(); an2[i] = __builtin_inff(); }

  for (int ct = 0; ct < 8; ++ct) {
    const int colbase = chunkbase + ct * 64;
    const int cb16 = colbase >> 4;

    // column metadata: issue early so loads fly during the MFMAs
    float sqc[4]; int tc[4];
    #pragma unroll
    for (int cf = 0; cf < 4; ++cf) {
      float2 m = meta[colbase + cf * 16 + l15];
      sqc[cf] = m.x; tc[cf] = __float_as_int(m.y);
    }

    f32x4 acc[2][4];
    #pragma unroll
    for (int rf = 0; rf < 2; ++rf)
      #pragma unroll
      for (int cf = 0; cf < 4; ++cf) acc[rf][cf] = (f32x4){0.f, 0.f, 0.f, 0.f};

    #pragma unroll
    for (int kk = 0; kk < 4; ++kk) {
      #pragma unroll
      for (int cf = 0; cf < 4; ++cf) {
        short8 b = xf[(cb16 + cf) * 256 + kk * 64 + l];
        acc[0][cf] = __builtin_amdgcn_mfma_f32_16x16x32_bf16(a[0][kk], b, acc[0][cf], 0, 0, 0);
        acc[1][cf] = __builtin_amdgcn_mfma_f32_16x16x32_bf16(a[1][kk], b, acc[1][cf], 0, 0, 0);
      }
    }

    // mining epilogue on v = sqc - 2s (monotone in d^2 per row)
    #pragma unroll
    for (int cf = 0; cf < 4; ++cf) {
      #pragma unroll
      for (int rf = 0; rf < 2; ++rf)
        #pragma unroll
        for (int rg = 0; rg < 4; ++rg) {
          int idx = rf * 4 + rg;
          float v = fmaf(-2.f, acc[rf][cf][rg], sqc[cf]);
          bool pos = (t_r[idx] == tc[cf]);
          ap2[idx] = pos ? fmaxf(ap2[idx], v) : ap2[idx];
          an2[idx] = pos ? an2[idx] : fminf(an2[idx], v);
        }
    }
  }

  // reduce across the 16 lanes (same l4 group = same rows, different cols)
  #pragma unroll
  for (int i = 0; i < 8; ++i) {
    #pragma unroll
    for (int off = 1; off < 16; off <<= 1) {
      ap2[i] = fmaxf(ap2[i], __shfl_xor(ap2[i], off));
      an2[i] = fminf(an2[i], __shfl_xor(an2[i], off));
    }
  }
  if (l15 == 0) {
    #pragma unroll
    for (int rf = 0; rf < 2; ++rf)
      #pragma unroll
      for (int rg = 0; rg < 4; ++rg) {
        int row = rb + rf * 16 + l4 * 4 + rg;
        float sqr = meta[row].x;
        // d^2 = v + sq_r; clamp >=1e-12 commutes with max/min; non-negative
        // floats are int-monotone -> int atomics give exact fp max/min.
        float a2 = fmaxf(ap2[rf * 4 + rg] + sqr, 1e-12f);
        float n2 = fmaxf(an2[rf * 4 + rg] + sqr, 1e-12f);
        atomicMax(apb + row, __float_as_int(a2));
        atomicMin(anb + row, __float_as_int(n2));
      }
  }
}

// ---------------- Kernel C: loss = mean(relu(sqrt(ap2)-sqrt(an2)+margin)) --
__global__ __launch_bounds__(1024) void loss_kernel(
    const int4v* __restrict__ apb, const int4v* __restrict__ anb,
    float* __restrict__ out) {
  __shared__ float red[16];
  float s = 0.f;
  for (int i = threadIdx.x; i < N_ROWS / 4; i += 1024) {
    int4v a4 = apb[i], n4 = anb[i];
    #pragma unroll
    for (int j = 0; j < 4; ++j) {
      float ap = sqrtf(__int_as_float(a4[j]));
      float an = sqrtf(__int_as_float(n4[j]));   // +inf sentinel -> relu(-inf)=0
      float li = ap - an + MARGIN_F;
      s += li > 0.f ? li : 0.f;
    }
  }
  #pragma unroll
  for (int off = 32; off >= 1; off >>= 1) s += __shfl_xor(s, off);
  const int w = threadIdx.x >> 6, l = threadIdx.x & 63;
  if (l == 0) red[w] = s;
  __syncthreads();
  if (threadIdx.x < 16) {
    float v = red[threadIdx.x];
    #pragma unroll
    for (int off = 8; off >= 1; off >>= 1) v += __shfl_xor(v, off);
    if (threadIdx.x == 0) out[0] = v / (float)N_ROWS;
  }
}

extern "C" void kernel_launch(void* const* d_in, const int* in_sizes, int n_in,
                              void* d_out, int out_size, void* d_ws, size_t ws_size,
                              hipStream_t stream) {
  const float* x = (const float*)d_in[0];
  const int* tgt = (const int*)d_in[1];
  float* out = (float*)d_out;

  char* ws = (char*)d_ws;
  unsigned short* xbB = (unsigned short*)ws;                // 2 MB fragment-major bf16
  float2* meta = (float2*)(ws + 2097152);                   // 64 KB (sq, tgt)
  int* apb = (int*)(ws + 2097152 + 65536);                  // 32 KB ap^2 bits
  int* anb = (int*)(ws + 2097152 + 65536 + 32768);          // 32 KB an^2 bits

  prep_kernel<<<2048, 256, 0, stream>>>(x, tgt, xbB, meta, apb, anb);
  gram_mine_kernel<<<dim3(64, 16), 256, 0, stream>>>(xbB, meta, apb, anb);
  loss_kernel<<<1, 1024, 0, stream>>>((const int4v*)apb, (const int4v*)anb, out);
}